// Round 1
// baseline (236.595 us; speedup 1.0000x reference)
//
#include <hip/hip_runtime.h>

// Problem constants (from reference: b=16, c=2048, h=56, w=56, K=3, PAD=1)
#define BATCH 16
#define CH    2048
#define HW    3136   // 56*56
#define HW4   784    // HW/4 (3136 % 4 == 0, so float4 chunks never cross planes)

// ---------------------------------------------------------------------------
// Kernel 1: per-(b,c) mean over the 56x56 plane.
// One block per plane; plane data is contiguous (NCHW). float4 loads.
// ---------------------------------------------------------------------------
__global__ __launch_bounds__(256) void mean_kernel(const float* __restrict__ x,
                                                   float* __restrict__ y) {
    const int plane = blockIdx.x;  // b*CH + c
    const float4* xp = reinterpret_cast<const float4*>(x) + (size_t)plane * HW4;

    float sum = 0.0f;
    for (int i = threadIdx.x; i < HW4; i += 256) {
        float4 v = xp[i];
        sum += (v.x + v.y) + (v.z + v.w);
    }
    // wave-64 butterfly reduce
    #pragma unroll
    for (int o = 32; o > 0; o >>= 1) sum += __shfl_down(sum, o, 64);

    __shared__ float part[4];
    const int lane = threadIdx.x & 63;
    const int wid  = threadIdx.x >> 6;
    if (lane == 0) part[wid] = sum;
    __syncthreads();
    if (threadIdx.x == 0) {
        float s = (part[0] + part[1]) + (part[2] + part[3]);
        y[plane] = s * (1.0f / (float)HW);
    }
}

// ---------------------------------------------------------------------------
// Kernel 2: gate[b][c] from y[b][:].
// offsets[b,k,c] = sum_j y[b, c+j-1] * w_offset[k,0,j]   (zero-padded, no flip)
// p = c + (k-1) + offsets; clip [0, C-1]; lerp-sample y; dot w_deform + bias;
// sigmoid. One block per batch; y row staged in LDS.
// ---------------------------------------------------------------------------
__global__ __launch_bounds__(256) void gate_kernel(const float* __restrict__ y,
                                                   const float* __restrict__ w_offset,
                                                   const float* __restrict__ w_deform,
                                                   const float* __restrict__ b_deform,
                                                   float* __restrict__ gate) {
    __shared__ float ly[CH];
    const int b = blockIdx.x;
    for (int i = threadIdx.x; i < CH; i += 256) ly[i] = y[b * CH + i];
    __syncthreads();

    float wo[9];
    #pragma unroll
    for (int i = 0; i < 9; ++i) wo[i] = w_offset[i];  // (k,0,j) row-major: wo[k*3+j]
    const float wd0 = w_deform[0], wd1 = w_deform[1], wd2 = w_deform[2];
    const float bd  = b_deform[0];

    for (int c = threadIdx.x; c < CH; c += 256) {
        const float ym = (c >= 1)      ? ly[c - 1] : 0.0f;  // zero padding
        const float y0 = ly[c];
        const float yp = (c < CH - 1)  ? ly[c + 1] : 0.0f;

        float acc = 0.0f;
        #pragma unroll
        for (int k = 0; k < 3; ++k) {
            const float off = ym * wo[k * 3 + 0] + y0 * wo[k * 3 + 1] + yp * wo[k * 3 + 2];
            float p = (float)c + (float)(k - 1) + off;
            p = fminf(fmaxf(p, 0.0f), (float)(CH - 1));
            const float p0 = floorf(p);
            const float fr = p - p0;
            const int i0 = (int)p0;
            const int i1 = min(i0 + 1, CH - 1);
            const float s = ly[i0] * (1.0f - fr) + ly[i1] * fr;
            const float wk = (k == 0) ? wd0 : (k == 1) ? wd1 : wd2;
            acc += s * wk;
        }
        const float v = acc + bd;
        gate[b * CH + c] = 1.0f / (1.0f + expf(-v));
    }
}

// ---------------------------------------------------------------------------
// Kernel 3: out = x * gate[plane], float4 in/out. One block per plane.
// ---------------------------------------------------------------------------
__global__ __launch_bounds__(256) void scale_kernel(const float* __restrict__ x,
                                                    const float* __restrict__ gate,
                                                    float* __restrict__ out) {
    const int plane = blockIdx.x;
    const float g = gate[plane];
    const float4* xp = reinterpret_cast<const float4*>(x)   + (size_t)plane * HW4;
    float4*       op = reinterpret_cast<float4*>(out)       + (size_t)plane * HW4;
    for (int i = threadIdx.x; i < HW4; i += 256) {
        float4 v = xp[i];
        v.x *= g; v.y *= g; v.z *= g; v.w *= g;
        op[i] = v;
    }
}

extern "C" void kernel_launch(void* const* d_in, const int* in_sizes, int n_in,
                              void* d_out, int out_size, void* d_ws, size_t ws_size,
                              hipStream_t stream) {
    const float* x        = (const float*)d_in[0];   // (16, 2048, 56, 56)
    const float* w_offset = (const float*)d_in[1];   // (3, 1, 3)
    const float* w_deform = (const float*)d_in[2];   // (3,)
    const float* b_deform = (const float*)d_in[3];   // (1,)
    float* out = (float*)d_out;

    float* y    = (float*)d_ws;                // BATCH*CH floats
    float* gate = y + (size_t)BATCH * CH;      // BATCH*CH floats

    mean_kernel<<<BATCH * CH, 256, 0, stream>>>(x, y);
    gate_kernel<<<BATCH, 256, 0, stream>>>(y, w_offset, w_deform, b_deform, gate);
    scale_kernel<<<BATCH * CH, 256, 0, stream>>>(x, gate, out);
}

// Round 2
// 193.716 us; speedup vs baseline: 1.2213x; 1.2213x over previous
//
#include <hip/hip_runtime.h>

// Problem constants (reference: b=16, c=2048, h=56, w=56, K=3, PAD=1)
#define BATCH   16
#define CH      2048
#define HW      3136   // 56*56
#define HW4     784    // HW/4 (3136 % 4 == 0 -> float4 chunks never cross planes)
#define NPLANES (BATCH * CH)

typedef float v4f __attribute__((ext_vector_type(4)));

// ---------------------------------------------------------------------------
// Kernel 1: per-(b,c) mean over the 56x56 plane.
// One block per plane; plane data is contiguous (NCHW). float4 loads.
// Normal (caching) loads on purpose: we WANT x lines resident in L3 so the
// scale kernel can hit them.
// ---------------------------------------------------------------------------
__global__ __launch_bounds__(256) void mean_kernel(const float* __restrict__ x,
                                                   float* __restrict__ y) {
    const int plane = blockIdx.x;  // b*CH + c
    const v4f* xp = reinterpret_cast<const v4f*>(x) + (size_t)plane * HW4;

    float sum = 0.0f;
    for (int i = threadIdx.x; i < HW4; i += 256) {
        v4f v = xp[i];
        sum += (v.x + v.y) + (v.z + v.w);
    }
    // wave-64 butterfly reduce
    #pragma unroll
    for (int o = 32; o > 0; o >>= 1) sum += __shfl_down(sum, o, 64);

    __shared__ float part[4];
    const int lane = threadIdx.x & 63;
    const int wid  = threadIdx.x >> 6;
    if (lane == 0) part[wid] = sum;
    __syncthreads();
    if (threadIdx.x == 0) {
        float s = (part[0] + part[1]) + (part[2] + part[3]);
        y[plane] = s * (1.0f / (float)HW);
    }
}

// ---------------------------------------------------------------------------
// Kernel 2: out = x * gate(plane). Gate computed per-block by thread 0 from
// the y row (few scalar cached loads — y is 128 KB, fully L2-resident).
//
// Plane order REVERSED vs the mean kernel so we consume the L3-resident tail
// of x first. Output stores are non-temporal so the 411 MB write stream does
// not evict x from L3.
//
// Gate math (matches jax reference):
//   offsets[k] = sum_j y[c+j-1] * w_offset[k,0,j]   (zero-padded)
//   p = c + (k-1) + offsets[k]; clip [0, C-1]; linear-interp sample of y;
//   gate = sigmoid( sum_k sample_k * w_deform[k] + b_deform )
// ---------------------------------------------------------------------------
__global__ __launch_bounds__(256) void scale_kernel(const float* __restrict__ x,
                                                    const float* __restrict__ y,
                                                    const float* __restrict__ w_offset,
                                                    const float* __restrict__ w_deform,
                                                    const float* __restrict__ b_deform,
                                                    float* __restrict__ out) {
    const int plane = (NPLANES - 1) - (int)blockIdx.x;  // reverse order
    __shared__ float sgate;

    if (threadIdx.x == 0) {
        const int b = plane >> 11;          // / CH
        const int c = plane & (CH - 1);     // % CH
        const float* yb = y + b * CH;

        const float ym = (c >= 1)      ? yb[c - 1] : 0.0f;  // zero padding
        const float y0 = yb[c];
        const float yp = (c < CH - 1)  ? yb[c + 1] : 0.0f;

        float acc = 0.0f;
        #pragma unroll
        for (int k = 0; k < 3; ++k) {
            const float off = ym * w_offset[k * 3 + 0]
                            + y0 * w_offset[k * 3 + 1]
                            + yp * w_offset[k * 3 + 2];
            float p = (float)c + (float)(k - 1) + off;
            p = fminf(fmaxf(p, 0.0f), (float)(CH - 1));
            const float p0 = floorf(p);
            const float fr = p - p0;
            const int i0 = (int)p0;
            const int i1 = min(i0 + 1, CH - 1);
            const float s = yb[i0] * (1.0f - fr) + yb[i1] * fr;
            acc += s * w_deform[k];
        }
        const float v = acc + b_deform[0];
        sgate = 1.0f / (1.0f + expf(-v));
    }
    __syncthreads();
    const float g = sgate;

    const v4f* xp = reinterpret_cast<const v4f*>(x)   + (size_t)plane * HW4;
    v4f*       op = reinterpret_cast<v4f*>(out)       + (size_t)plane * HW4;
    for (int i = threadIdx.x; i < HW4; i += 256) {
        v4f v = xp[i];            // normal load: may hit L3 for tail planes
        v *= g;
        __builtin_nontemporal_store(v, &op[i]);  // don't evict x with writes
    }
}

extern "C" void kernel_launch(void* const* d_in, const int* in_sizes, int n_in,
                              void* d_out, int out_size, void* d_ws, size_t ws_size,
                              hipStream_t stream) {
    const float* x        = (const float*)d_in[0];   // (16, 2048, 56, 56)
    const float* w_offset = (const float*)d_in[1];   // (3, 1, 3)
    const float* w_deform = (const float*)d_in[2];   // (3,)
    const float* b_deform = (const float*)d_in[3];   // (1,)
    float* out = (float*)d_out;

    float* y = (float*)d_ws;                          // BATCH*CH floats

    mean_kernel<<<NPLANES, 256, 0, stream>>>(x, y);
    scale_kernel<<<NPLANES, 256, 0, stream>>>(x, y, w_offset, w_deform, b_deform, out);
}